// Round 9
// baseline (262.652 us; speedup 1.0000x reference)
//
#include <hip/hip_runtime.h>

// AUAvULoss — *** ROUND 9 = DIAGNOSTIC ROUND #2 ***
// R2-R8 invariant: total 58.2 = pass1 (24.6, measured R7) + REST 33.6us.
// REST is insensitive to pass2 compute (R8 null) and has never been observed.
// This round: pass2 sample-loop x16 (flush scaled 1/16) and final_k
// read/reduce x8 (idempotent) so BOTH surface in rocprof top-5 with real
// dur/FETCH/VALUBusy. Pipeline numerics otherwise identical to R8 (passed).

constexpr int C     = 8;
constexpr int NTH   = 21;
constexpr int NB    = 22;
constexpr int NREPS2 = 16;    // DIAGNOSTIC: pass2 sample-loop amplification
constexpr int FREPS  = 8;     // DIAGNOSTIC: final_k reduce amplification
constexpr int NBLK1 = 2048;
constexpr int BS1   = 256;
constexpr int NBLK2 = 512;
constexpr int BS2   = 512;
constexpr int NREP  = 32;     // LDS hist replicas
constexpr int RSTR  = 89;
constexpr float LOG_FEPS = -18.420680743952367f;  // logf(1e-8f)

struct Accum {
  int   l0;
  float f_part[NBLK1], c_part[NBLK1], mn_part[NBLK1], mx_part[NBLK1];
};

template <bool STASH>
__global__ __launch_bounds__(BS1) void pass1_k(const float4* __restrict__ p4,
                                               const float4* __restrict__ y4,
                                               const float4* __restrict__ w4,
                                               const float*  __restrict__ yraw,
                                               Accum* __restrict__ acc,
                                               float* __restrict__ su,
                                               float* __restrict__ sq1,
                                               float* __restrict__ sq2, int N) {
  __shared__ int sh_l0;
  if (threadIdx.x == 0) {
    float best = yraw[0]; int bi = 0;
#pragma unroll
    for (int j = 1; j < C; ++j) { if (yraw[j] > best) { best = yraw[j]; bi = j; } }
    sh_l0 = bi;
    if (blockIdx.x == 0) acc->l0 = bi;
  }
  __syncthreads();
  const int l0   = sh_l0;
  const int q    = threadIdx.x & 1;
  const int T    = blockIdx.x * BS1 + threadIdx.x;
  const int S    = NBLK1 * BS1;
  const int twoN = 2 * N;

  float fsum = 0.f, csum = 0.f;
  float umin = __uint_as_float(0x7F800000u), umax = 0.f;

  for (int idx = T; idx < twoN; idx += S) {
    float4 pv = p4[idx];
    float4 yv = y4[idx];
    float4 wv = w4[idx];
    float P[4] = {pv.x, pv.y, pv.z, pv.w};
    float Y[4] = {yv.x, yv.y, yv.z, yv.w};
    float W[4] = {wv.x, wv.y, wv.z, wv.w};
    float up = 0.f, cep = 0.f, fop = 0.f;
    float cmax = P[0]; int pid = 0;
#pragma unroll
    for (int j = 0; j < 4; ++j) {
      if (j > 0 && P[j] > cmax) { cmax = P[j]; pid = j; }
      float le = __logf(fmaxf(P[j], 1e-10f));
      up -= P[j] * le;
      float lf = fmaxf(le, LOG_FEPS);
      float t  = Y[j] * lf;
      cep -= t; fop -= t * W[j];
    }
    pid += 4 * q;
    fsum += fop; csum += cep;
    float unc = up + __shfl_xor(up, 1);
    float oc  = __shfl_xor(cmax, 1);
    int   op  = __shfl_xor(pid, 1);
    float lo_c = q ? oc : cmax;  int lo_p = q ? op : pid;
    float hi_c = q ? cmax : oc;  int hi_p = q ? pid : op;
    float conf = (hi_c > lo_c) ? hi_c : lo_c;
    int   pred = (hi_c > lo_c) ? hi_p : lo_p;
    umin = fminf(umin, unc); umax = fmaxf(umax, unc);
    if (STASH && q == 0) {
      bool  corr = (pred == l0);
      float tu   = tanhf(unc);
      float base = corr ? conf : (1.f - conf);
      float q1   = base * (1.f - tu);
      float q2   = base * tu;
      int   i    = idx >> 1;
      su[i]  = unc;
      sq1[i] = corr ? q1 : -q1;
      sq2[i] = corr ? q2 : -q2;
    }
  }

  float v0 = fsum, v1 = csum, v2 = umin, v3 = umax;
#pragma unroll
  for (int o = 32; o > 0; o >>= 1) {
    v0 += __shfl_down(v0, o); v1 += __shfl_down(v1, o);
    v2 = fminf(v2, __shfl_down(v2, o)); v3 = fmaxf(v3, __shfl_down(v3, o));
  }
  __shared__ float r0[4], r1[4], r2[4], r3[4];
  int ln = threadIdx.x & 63, wd = threadIdx.x >> 6;
  if (ln == 0) { r0[wd] = v0; r1[wd] = v1; r2[wd] = v2; r3[wd] = v3; }
  __syncthreads();
  if (threadIdx.x == 0) {
    acc->f_part[blockIdx.x]  = r0[0] + r0[1] + r0[2] + r0[3];
    acc->c_part[blockIdx.x]  = r1[0] + r1[1] + r1[2] + r1[3];
    acc->mn_part[blockIdx.x] = fminf(fminf(r2[0], r2[1]), fminf(r2[2], r2[3]));
    acc->mx_part[blockIdx.x] = fmaxf(fmaxf(r3[0], r3[1]), fmaxf(r3[2], r3[3]));
  }
}

__device__ __forceinline__ void reduce_minmax(const Accum* __restrict__ acc,
                                              float& out_umin, float& out_scale) {
  __shared__ float rmn[BS2 / 64], rmx[BS2 / 64];
  __shared__ float sh_umin, sh_umax;
  float mn = __uint_as_float(0x7F800000u), mx = 0.f;
  for (int i = threadIdx.x; i < NBLK1; i += BS2) {
    mn = fminf(mn, acc->mn_part[i]);
    mx = fmaxf(mx, acc->mx_part[i]);
  }
#pragma unroll
  for (int o = 32; o > 0; o >>= 1) {
    mn = fminf(mn, __shfl_down(mn, o));
    mx = fmaxf(mx, __shfl_down(mx, o));
  }
  int lane = threadIdx.x & 63, wid = threadIdx.x >> 6;
  if (lane == 0) { rmn[wid] = mn; rmx[wid] = mx; }
  __syncthreads();
  if (threadIdx.x == 0) {
    float a = rmn[0], b = rmx[0];
#pragma unroll
    for (int wv = 1; wv < BS2 / 64; ++wv) { a = fminf(a, rmn[wv]); b = fmaxf(b, rmx[wv]); }
    sh_umin = a; sh_umax = b;
  }
  __syncthreads();
  out_umin = sh_umin; out_scale = sh_umax - sh_umin;
}

__device__ __forceinline__ int bin_of(float u, float umin, float scale) {
  int t0 = NB - 1;
#pragma unroll
  for (int t = NTH - 1; t >= 0; --t) {
    float thr = umin + ((float)t * 0.05f) * scale;
    if (u <= thr) t0 = t;
  }
  return t0;
}

__global__ __launch_bounds__(BS2) void pass2_k(const float* __restrict__ su,
                                               const float* __restrict__ sq1,
                                               const float* __restrict__ sq2,
                                               const Accum* __restrict__ acc,
                                               float* __restrict__ partial2, int N) {
  __shared__ float h[NREP * RSTR];
  for (int k = threadIdx.x; k < NREP * RSTR; k += BS2) h[k] = 0.f;
  float umin, scale;
  reduce_minmax(acc, umin, scale);
  float* hb = &h[(threadIdx.x & (NREP - 1)) * RSTR];
  int stride = gridDim.x * blockDim.x;
  for (int rep = 0; rep < NREPS2; ++rep) {          // DIAGNOSTIC x16
    for (int i = blockIdx.x * blockDim.x + threadIdx.x; i < N; i += stride) {
      float u   = su[i];
      float q1s = sq1[i];
      float q2s = sq2[i];
      int t0  = bin_of(u, umin, scale);
      int row = (int)(__float_as_uint(q1s) >> 31) * 2;
      atomicAdd(&hb[row * NB + t0],       fabsf(q1s));
      atomicAdd(&hb[(row + 1) * NB + t0], fabsf(q2s));
    }
  }
  __syncthreads();
  const float inv = 1.0f / (float)NREPS2;           // undo amplification
  for (int idx = threadIdx.x; idx < 4 * NB; idx += BS2) {
    float s = 0.f;
#pragma unroll
    for (int r = 0; r < NREP; ++r) s += h[r * RSTR + idx];
    partial2[idx * NBLK2 + blockIdx.x] = s * inv;
  }
}

__global__ __launch_bounds__(BS2) void pass2f_k(const float4* __restrict__ p4,
                                                const Accum* __restrict__ acc,
                                                float* __restrict__ partial2, int N) {
  __shared__ float h[NREP * RSTR];
  for (int k = threadIdx.x; k < NREP * RSTR; k += BS2) h[k] = 0.f;
  float umin, scale;
  reduce_minmax(acc, umin, scale);
  const int l0 = acc->l0;
  float* hb = &h[(threadIdx.x & (NREP - 1)) * RSTR];
  int stride = gridDim.x * blockDim.x;
  for (int i = blockIdx.x * blockDim.x + threadIdx.x; i < N; i += stride) {
    float4 a = p4[2 * i], b = p4[2 * i + 1];
    float p[8] = {a.x, a.y, a.z, a.w, b.x, b.y, b.z, b.w};
    float conf = p[0]; int pred = 0;
    float unc = 0.f;
#pragma unroll
    for (int j = 0; j < 8; ++j) {
      if (p[j] > conf) { conf = p[j]; pred = j; }
      unc -= p[j] * __logf(fmaxf(p[j], 1e-10f));
    }
    bool corr = (pred == l0);
    float tu = tanhf(unc);
    float base = corr ? conf : (1.f - conf);
    int t0 = bin_of(unc, umin, scale);
    int row = corr ? 0 : 2;
    atomicAdd(&hb[row * NB + t0],       base * (1.f - tu));
    atomicAdd(&hb[(row + 1) * NB + t0], base * tu);
  }
  __syncthreads();
  for (int idx = threadIdx.x; idx < 4 * NB; idx += BS2) {
    float s = 0.f;
#pragma unroll
    for (int r = 0; r < NREP; ++r) s += h[r * RSTR + idx];
    partial2[idx * NBLK2 + blockIdx.x] = s;
  }
}

__global__ __launch_bounds__(1024) void final_k(const float* __restrict__ partial2,
                                                const Accum* __restrict__ acc,
                                                float* __restrict__ out, int N) {
  __shared__ float hist[4 * NB];
  __shared__ double df[16], dc[16];
  __shared__ float sh_f, sh_c;
  int lane = threadIdx.x & 63, wid = threadIdx.x >> 6;

  for (int rep = 0; rep < FREPS; ++rep) {           // DIAGNOSTIC x8 (idempotent)
    double f = 0.0, c = 0.0;
    for (int i = threadIdx.x; i < NBLK1; i += 1024) {
      f += (double)acc->f_part[i]; c += (double)acc->c_part[i];
    }
#pragma unroll
    for (int o = 32; o > 0; o >>= 1) { f += __shfl_down(f, o); c += __shfl_down(c, o); }
    if (lane == 0) { df[wid] = f; dc[wid] = c; }

    for (int cidx = wid; cidx < 4 * NB; cidx += 16) {
      float s = 0.f;
      for (int k = lane; k < NBLK2; k += 64) s += partial2[cidx * NBLK2 + k];
#pragma unroll
      for (int o = 32; o > 0; o >>= 1) s += __shfl_down(s, o);
      if (lane == 0) hist[cidx] = s;
    }
    __syncthreads();
  }
  if (threadIdx.x == 0) {
    double ft = 0.0, ct = 0.0;
#pragma unroll
    for (int wv = 0; wv < 16; ++wv) { ft += df[wv]; ct += dc[wv]; }
    sh_f = (float)ft; sh_c = (float)ct;

    const float *hac = &hist[0], *hau = &hist[NB], *hic = &hist[2 * NB], *hiu = &hist[3 * NB];
    float tot_au = 0.f, tot_iu = 0.f;
    for (int s = 0; s < NB; ++s) { tot_au += hau[s]; tot_iu += hiu[s]; }
    float pac = 0.f, pau = 0.f, pic = 0.f, piu = 0.f, auc = 0.f, prev = 0.f;
    for (int t = 0; t < NTH; ++t) {
      pac += hac[t]; pau += hau[t]; pic += hic[t]; piu += hiu[t];
      float n_ac = pac, n_au = tot_au - pau, n_ic = pic, n_iu = tot_iu - piu;
      float avu = (n_ac + n_iu) / (n_ac + n_au + n_ic + n_iu + 1e-10f);
      if (t > 0) auc += 0.5f * (avu + prev) * 0.05f;
      prev = avu;
    }
    out[0] = -logf(auc + 1e-10f) + sh_f / (float)N;
    out[1] = sh_c / (float)N;
  }
}

extern "C" void kernel_launch(void* const* d_in, const int* in_sizes, int n_in,
                              void* d_out, int out_size, void* d_ws, size_t ws_size,
                              hipStream_t stream) {
  const float* probs = (const float*)d_in[0];
  const float* y     = (const float*)d_in[1];
  const float* w     = (const float*)d_in[2];
  float* out = (float*)d_out;
  int N = in_sizes[0] / C;

  Accum* acc = (Accum*)d_ws;
  size_t off_p2 = (sizeof(Accum) + 255) & ~(size_t)255;
  size_t off_su = (off_p2 + (size_t)(4 * NB) * NBLK2 * sizeof(float) + 255) & ~(size_t)255;
  size_t one    = ((size_t)N * sizeof(float) + 255) & ~(size_t)255;
  size_t need   = off_su + 3 * one;
  float* partial2 = (float*)((char*)d_ws + off_p2);
  float* su  = (float*)((char*)d_ws + off_su);
  float* sq1 = (float*)((char*)d_ws + off_su + one);
  float* sq2 = (float*)((char*)d_ws + off_su + 2 * one);

  if (ws_size >= need) {
    pass1_k<true><<<NBLK1, BS1, 0, stream>>>((const float4*)probs, (const float4*)y,
                                             (const float4*)w, y, acc, su, sq1, sq2, N);
    pass2_k<<<NBLK2, BS2, 0, stream>>>(su, sq1, sq2, acc, partial2, N);
  } else {
    pass1_k<false><<<NBLK1, BS1, 0, stream>>>((const float4*)probs, (const float4*)y,
                                              (const float4*)w, y, acc,
                                              nullptr, nullptr, nullptr, N);
    pass2f_k<<<NBLK2, BS2, 0, stream>>>((const float4*)probs, acc, partial2, N);
  }
  final_k<<<1, 1024, 0, stream>>>(partial2, acc, out, N);
}

// Round 10
// 57.500 us; speedup vs baseline: 4.5679x; 4.5679x over previous
//
#include <hip/hip_runtime.h>

// AUAvULoss: probs[N,8], y[N,8] one-hot, weights[N,8] -> (avu_loss, CE_loss)
//
// Budget (R7/R9 measured): pass1 24.7us | pass2 10.9 (latency-bound) |
// final 6.5 (single-block L2 pull) | launch gaps ~16 across 3 dispatches.
// R10: 2 kernels. pass2 = float4-batched 4 samples/thread (breaks dependent
// chains) + LDS hist + global-atomic flush into ghist[16][88] + LAST-BLOCK-
// DONE final (one fence+atomic per block; coherent readback via
// atomicAdd(x,0)). No grid.sync (R3: 426us). pass1 unchanged except stash
// shrinks to (u, +-base) — tanh recomputed in pass2 where VALU idles at 13%.

constexpr int C     = 8;
constexpr int NTH   = 21;
constexpr int NB    = 22;       // 0..20 = first threshold satisfied; 21 = none
constexpr int NBLK1 = 2048;
constexpr int BS1   = 256;
constexpr int NBLK2 = 1024;
constexpr int BS2   = 256;
constexpr int NBLK2F = 512;     // fallback (no-stash) config
constexpr int BS2F   = 512;
constexpr int NREP  = 32;       // LDS hist replicas
constexpr int RSTR  = 89;       // replica stride (odd -> distinct banks)
constexpr int GREP  = 16;       // global hist replicas
constexpr float LOG_FEPS = -18.420680743952367f;  // logf(1e-8f)

struct Accum {
  int   l0;
  float f_part[NBLK1], c_part[NBLK1], mn_part[NBLK1], mx_part[NBLK1];
  float ghist[GREP][4 * NB];
  int   done[64];               // padded counter line
};

template <bool STASH>
__global__ __launch_bounds__(BS1) void pass1_k(const float4* __restrict__ p4,
                                               const float4* __restrict__ y4,
                                               const float4* __restrict__ w4,
                                               const float*  __restrict__ yraw,
                                               Accum* __restrict__ acc,
                                               float* __restrict__ su,
                                               float* __restrict__ sb, int N) {
  __shared__ int sh_l0;
  if (blockIdx.x == 0) {        // zero ghist + done (visible at kernel boundary)
    for (int i = threadIdx.x; i < GREP * 4 * NB; i += BS1) ((float*)acc->ghist)[i] = 0.f;
    if (threadIdx.x == 0) acc->done[0] = 0;
  }
  if (threadIdx.x == 0) {
    float best = yraw[0]; int bi = 0;
#pragma unroll
    for (int j = 1; j < C; ++j) { if (yraw[j] > best) { best = yraw[j]; bi = j; } }
    sh_l0 = bi;
    if (blockIdx.x == 0) acc->l0 = bi;
  }
  __syncthreads();
  const int l0   = sh_l0;
  const int q    = threadIdx.x & 1;          // channel half (0: ch0-3, 1: ch4-7)
  const int T    = blockIdx.x * BS1 + threadIdx.x;
  const int S    = NBLK1 * BS1;
  const int twoN = 2 * N;                    // f4s per array (even; pairs intact)

  float fsum = 0.f, csum = 0.f;
  float umin = __uint_as_float(0x7F800000u), umax = 0.f;

  for (int idx = T; idx < twoN; idx += S) {
    float4 pv = p4[idx];
    float4 yv = y4[idx];
    float4 wv = w4[idx];
    float P[4] = {pv.x, pv.y, pv.z, pv.w};
    float Y[4] = {yv.x, yv.y, yv.z, yv.w};
    float W[4] = {wv.x, wv.y, wv.z, wv.w};
    float up = 0.f, cep = 0.f, fop = 0.f;
    float cmax = P[0]; int pid = 0;
#pragma unroll
    for (int j = 0; j < 4; ++j) {
      if (j > 0 && P[j] > cmax) { cmax = P[j]; pid = j; }  // first-occurrence
      float le = __logf(fmaxf(P[j], 1e-10f));              // entropy log (EPS=1e-10)
      up -= P[j] * le;
      float lf = fmaxf(le, LOG_FEPS);                      // = log(max(p,1e-8))
      float t  = Y[j] * lf;
      cep -= t; fop -= t * W[j];
    }
    pid += 4 * q;
    fsum += fop; csum += cep;                // each lane adds its own half
    float unc = up + __shfl_xor(up, 1);
    float oc  = __shfl_xor(cmax, 1);
    int   op  = __shfl_xor(pid, 1);
    float lo_c = q ? oc : cmax;  int lo_p = q ? op : pid;
    float hi_c = q ? cmax : oc;  int hi_p = q ? pid : op;
    float conf = (hi_c > lo_c) ? hi_c : lo_c;   // ties -> low half (first occ.)
    int   pred = (hi_c > lo_c) ? hi_p : lo_p;
    umin = fminf(umin, unc); umax = fmaxf(umax, unc);
    if (STASH && q == 0) {                   // even lanes own the sample
      bool  corr = (pred == l0);
      float base = corr ? conf : (1.f - conf);
      int   i    = idx >> 1;
      su[i] = unc;
      sb[i] = corr ? base : -base;           // sign bit = !correct
    }
  }

  float v0 = fsum, v1 = csum, v2 = umin, v3 = umax;
#pragma unroll
  for (int o = 32; o > 0; o >>= 1) {
    v0 += __shfl_down(v0, o); v1 += __shfl_down(v1, o);
    v2 = fminf(v2, __shfl_down(v2, o)); v3 = fmaxf(v3, __shfl_down(v3, o));
  }
  __shared__ float r0[4], r1[4], r2[4], r3[4];
  int ln = threadIdx.x & 63, wd = threadIdx.x >> 6;
  if (ln == 0) { r0[wd] = v0; r1[wd] = v1; r2[wd] = v2; r3[wd] = v3; }
  __syncthreads();
  if (threadIdx.x == 0) {
    acc->f_part[blockIdx.x]  = r0[0] + r0[1] + r0[2] + r0[3];
    acc->c_part[blockIdx.x]  = r1[0] + r1[1] + r1[2] + r1[3];
    acc->mn_part[blockIdx.x] = fminf(fminf(r2[0], r2[1]), fminf(r2[2], r2[3]));
    acc->mx_part[blockIdx.x] = fmaxf(fmaxf(r3[0], r3[1]), fmaxf(r3[2], r3[3]));
  }
}

template <int BS>
__device__ __forceinline__ void reduce_minmax(const Accum* __restrict__ acc,
                                              float& out_umin, float& out_scale) {
  __shared__ float rmn[BS / 64], rmx[BS / 64];
  __shared__ float sh_umin, sh_umax;
  float mn = __uint_as_float(0x7F800000u), mx = 0.f;
  for (int i = threadIdx.x; i < NBLK1; i += BS) {
    mn = fminf(mn, acc->mn_part[i]);
    mx = fmaxf(mx, acc->mx_part[i]);
  }
#pragma unroll
  for (int o = 32; o > 0; o >>= 1) {
    mn = fminf(mn, __shfl_down(mn, o));
    mx = fmaxf(mx, __shfl_down(mx, o));
  }
  int lane = threadIdx.x & 63, wid = threadIdx.x >> 6;
  if (lane == 0) { rmn[wid] = mn; rmx[wid] = mx; }
  __syncthreads();
  if (threadIdx.x == 0) {
    float a = rmn[0], b = rmx[0];
#pragma unroll
    for (int wv = 1; wv < BS / 64; ++wv) { a = fminf(a, rmn[wv]); b = fmaxf(b, rmx[wv]); }
    sh_umin = a; sh_umax = b;
  }
  __syncthreads();
  out_umin = sh_umin; out_scale = sh_umax - sh_umin;
}

// Branchless first-satisfied-threshold (bit-identical comparisons to reference).
__device__ __forceinline__ int bin_of(float u, float umin, float scale) {
  int t0 = NB - 1;
#pragma unroll
  for (int t = NTH - 1; t >= 0; --t) {
    float thr = umin + ((float)t * 0.05f) * scale;
    if (u <= thr) t0 = t;                 // cndmask, no branch
  }
  return t0;
}

__device__ __forceinline__ void epilogue(const float* hist, double fsum, double csum,
                                         float* out, int N) {
  const float *hac = &hist[0], *hau = &hist[NB], *hic = &hist[2 * NB], *hiu = &hist[3 * NB];
  float tot_au = 0.f, tot_iu = 0.f;
  for (int s = 0; s < NB; ++s) { tot_au += hau[s]; tot_iu += hiu[s]; }
  float pac = 0.f, pau = 0.f, pic = 0.f, piu = 0.f, auc = 0.f, prev = 0.f;
  for (int t = 0; t < NTH; ++t) {
    pac += hac[t]; pau += hau[t]; pic += hic[t]; piu += hiu[t];
    float n_ac = pac, n_au = tot_au - pau, n_ic = pic, n_iu = tot_iu - piu;
    float avu = (n_ac + n_iu) / (n_ac + n_au + n_ic + n_iu + 1e-10f);
    if (t > 0) auc += 0.5f * (avu + prev) * 0.05f;
    prev = avu;
  }
  out[0] = -logf(auc + 1e-10f) + (float)(fsum / (double)N);  // BETA = 1
  out[1] = (float)(csum / (double)N);
}

__global__ __launch_bounds__(BS2) void pass2_k(const float4* __restrict__ su4,
                                               const float4* __restrict__ sb4,
                                               Accum* __restrict__ acc,
                                               float* __restrict__ out, int N) {
  __shared__ float h[NREP * RSTR];
  for (int k = threadIdx.x; k < NREP * RSTR; k += BS2) h[k] = 0.f;
  float umin, scale;
  reduce_minmax<BS2>(acc, umin, scale);   // contains __syncthreads (covers h init)
  float* hb = &h[(threadIdx.x & (NREP - 1)) * RSTR];
  const int n4 = (N + 3) >> 2;
  const int stride = gridDim.x * BS2;
  for (int i4 = blockIdx.x * BS2 + threadIdx.x; i4 < n4; i4 += stride) {
    float4 u4 = su4[i4];                   // 4 samples in 2 loads (ILP)
    float4 b4 = sb4[i4];
    float U[4] = {u4.x, u4.y, u4.z, u4.w};
    float B[4] = {b4.x, b4.y, b4.z, b4.w};
    int rem = N - (i4 << 2);
#pragma unroll
    for (int k = 0; k < 4; ++k) {
      if (k < rem) {
        float u = U[k], bs = B[k];
        float tu   = tanhf(u);
        float base = fabsf(bs);
        int   row  = (int)(__float_as_uint(bs) >> 31) * 2;  // sign = !correct
        int   t0   = bin_of(u, umin, scale);
        atomicAdd(&hb[row * NB + t0],       base * (1.f - tu));
        atomicAdd(&hb[(row + 1) * NB + t0], base * tu);
      }
    }
  }
  __syncthreads();
  for (int idx = threadIdx.x; idx < 4 * NB; idx += BS2) {
    float s = 0.f;
#pragma unroll
    for (int r = 0; r < NREP; ++r) s += h[r * RSTR + idx];
    if (s != 0.f) atomicAdd(&acc->ghist[blockIdx.x & (GREP - 1)][idx], s);
  }
  __shared__ int amLast;
  __syncthreads();                         // drains flush atomics (vmcnt)
  if (threadIdx.x == 0) {
    __threadfence();                       // release: 1 per block, staggered
    amLast = (atomicAdd(&acc->done[0], 1) == (int)gridDim.x - 1);
  }
  __syncthreads();
  if (!amLast) return;

  // ---------- last block: final reduce + epilogue ----------
  __shared__ float gh[GREP * 4 * NB];      // 5.6 KB
  for (int j = threadIdx.x; j < GREP * 4 * NB; j += BS2)
    gh[j] = atomicAdd(&((float*)acc->ghist)[j], 0.0f);   // coherent cross-XCD read
  double f = 0.0, c = 0.0;
  for (int i = threadIdx.x; i < NBLK1; i += BS2) {
    f += (double)acc->f_part[i]; c += (double)acc->c_part[i];
  }
#pragma unroll
  for (int o = 32; o > 0; o >>= 1) { f += __shfl_down(f, o); c += __shfl_down(c, o); }
  __shared__ double df[BS2 / 64], dc[BS2 / 64];
  int lane = threadIdx.x & 63, wid = threadIdx.x >> 6;
  if (lane == 0) { df[wid] = f; dc[wid] = c; }
  __shared__ float hist[4 * NB];
  __syncthreads();
  if (threadIdx.x < 4 * NB) {
    float s = 0.f;
#pragma unroll
    for (int r = 0; r < GREP; ++r) s += gh[r * 4 * NB + threadIdx.x];
    hist[threadIdx.x] = s;
  }
  __syncthreads();
  if (threadIdx.x == 0) {
    double ft = 0.0, ct = 0.0;
#pragma unroll
    for (int wv = 0; wv < BS2 / 64; ++wv) { ft += df[wv]; ct += dc[wv]; }
    epilogue(hist, ft, ct, out, N);
  }
}

// ---------------- fallback path (no stash space): proven R8 structure ----------------
__global__ __launch_bounds__(BS2F) void pass2f_k(const float4* __restrict__ p4,
                                                 const Accum* __restrict__ acc,
                                                 float* __restrict__ partial2, int N) {
  __shared__ float h[NREP * RSTR];
  for (int k = threadIdx.x; k < NREP * RSTR; k += BS2F) h[k] = 0.f;
  float umin, scale;
  reduce_minmax<BS2F>(acc, umin, scale);
  const int l0 = acc->l0;
  float* hb = &h[(threadIdx.x & (NREP - 1)) * RSTR];
  int stride = gridDim.x * blockDim.x;
  for (int i = blockIdx.x * blockDim.x + threadIdx.x; i < N; i += stride) {
    float4 a = p4[2 * i], b = p4[2 * i + 1];
    float p[8] = {a.x, a.y, a.z, a.w, b.x, b.y, b.z, b.w};
    float conf = p[0]; int pred = 0;
    float unc = 0.f;
#pragma unroll
    for (int j = 0; j < 8; ++j) {
      if (p[j] > conf) { conf = p[j]; pred = j; }
      unc -= p[j] * __logf(fmaxf(p[j], 1e-10f));
    }
    bool corr = (pred == l0);
    float tu = tanhf(unc);
    float base = corr ? conf : (1.f - conf);
    int t0 = bin_of(unc, umin, scale);
    int row = corr ? 0 : 2;
    atomicAdd(&hb[row * NB + t0],       base * (1.f - tu));
    atomicAdd(&hb[(row + 1) * NB + t0], base * tu);
  }
  __syncthreads();
  for (int idx = threadIdx.x; idx < 4 * NB; idx += BS2F) {
    float s = 0.f;
#pragma unroll
    for (int r = 0; r < NREP; ++r) s += h[r * RSTR + idx];
    partial2[idx * NBLK2F + blockIdx.x] = s;
  }
}

__global__ __launch_bounds__(1024) void final_k(const float* __restrict__ partial2,
                                                const Accum* __restrict__ acc,
                                                float* __restrict__ out, int N) {
  __shared__ float hist[4 * NB];
  __shared__ double df[16], dc[16];
  int lane = threadIdx.x & 63, wid = threadIdx.x >> 6;
  double f = 0.0, c = 0.0;
  for (int i = threadIdx.x; i < NBLK1; i += 1024) {
    f += (double)acc->f_part[i]; c += (double)acc->c_part[i];
  }
#pragma unroll
  for (int o = 32; o > 0; o >>= 1) { f += __shfl_down(f, o); c += __shfl_down(c, o); }
  if (lane == 0) { df[wid] = f; dc[wid] = c; }
  for (int cidx = wid; cidx < 4 * NB; cidx += 16) {
    float s = 0.f;
    for (int k = lane; k < NBLK2F; k += 64) s += partial2[cidx * NBLK2F + k];
#pragma unroll
    for (int o = 32; o > 0; o >>= 1) s += __shfl_down(s, o);
    if (lane == 0) hist[cidx] = s;
  }
  __syncthreads();
  if (threadIdx.x == 0) {
    double ft = 0.0, ct = 0.0;
#pragma unroll
    for (int wv = 0; wv < 16; ++wv) { ft += df[wv]; ct += dc[wv]; }
    epilogue(hist, ft, ct, out, N);
  }
}

extern "C" void kernel_launch(void* const* d_in, const int* in_sizes, int n_in,
                              void* d_out, int out_size, void* d_ws, size_t ws_size,
                              hipStream_t stream) {
  const float* probs = (const float*)d_in[0];
  const float* y     = (const float*)d_in[1];
  const float* w     = (const float*)d_in[2];
  float* out = (float*)d_out;
  int N = in_sizes[0] / C;

  Accum* acc = (Accum*)d_ws;
  size_t off_p2 = (sizeof(Accum) + 255) & ~(size_t)255;
  size_t off_su = (off_p2 + (size_t)(4 * NB) * NBLK2F * sizeof(float) + 255) & ~(size_t)255;
  size_t one    = ((size_t)N * sizeof(float) + 255) & ~(size_t)255;
  size_t need   = off_su + 2 * one;
  float* partial2 = (float*)((char*)d_ws + off_p2);
  float* su = (float*)((char*)d_ws + off_su);
  float* sb = (float*)((char*)d_ws + off_su + one);

  if (ws_size >= need) {
    pass1_k<true><<<NBLK1, BS1, 0, stream>>>((const float4*)probs, (const float4*)y,
                                             (const float4*)w, y, acc, su, sb, N);
    pass2_k<<<NBLK2, BS2, 0, stream>>>((const float4*)su, (const float4*)sb, acc, out, N);
  } else {
    pass1_k<false><<<NBLK1, BS1, 0, stream>>>((const float4*)probs, (const float4*)y,
                                              (const float4*)w, y, acc, nullptr, nullptr, N);
    pass2f_k<<<NBLK2F, BS2F, 0, stream>>>((const float4*)probs, acc, partial2, N);
    final_k<<<1, 1024, 0, stream>>>(partial2, acc, out, N);
  }
}

// Round 11
// 52.413 us; speedup vs baseline: 5.0112x; 1.0970x over previous
//
#include <hip/hip_runtime.h>

// AUAvULoss: probs[N,8], y[N,8] one-hot, weights[N,8] -> (avu_loss, CE_loss)
//
// Fitted budget (R7-R10): FIXED replay overhead ~15us | pass1 24.7us |
// pass2 sample-loop ~10.8 (latency-bound) | final-reduce ~6 | per-dispatch
// gap ~0.3us. R10's last-block tail cost ~6us (RMW readback + deep flush
// chains) — this round keeps the 2-kernel structure but makes the tail cheap:
//   * readback via __hip_atomic_load(RELAXED, AGENT) — coherent cross-XCD
//     LOAD (rocPRIM decoupled-lookback pattern), staged through LDS, parallel
//   * 512 blocks (flush chains 32/address, half the fences)
//   * 8 samples/thread via two float4-pairs issued before compute (ILP)
// pass1 byte-identical to R10 (measured). No grid.sync (R3: 426us disaster).

constexpr int C     = 8;
constexpr int NTH   = 21;
constexpr int NB    = 22;       // 0..20 = first threshold satisfied; 21 = none
constexpr int NBLK1 = 2048;
constexpr int BS1   = 256;
constexpr int NBLK2 = 512;
constexpr int BS2   = 256;
constexpr int NBLK2F = 512;     // fallback (no-stash) config
constexpr int BS2F   = 512;
constexpr int NREP  = 32;       // LDS hist replicas
constexpr int RSTR  = 89;       // replica stride (odd -> distinct banks)
constexpr int GREP  = 16;       // global hist replicas
constexpr float LOG_FEPS = -18.420680743952367f;  // logf(1e-8f)

struct Accum {
  int   l0;
  float f_part[NBLK1], c_part[NBLK1], mn_part[NBLK1], mx_part[NBLK1];
  float ghist[GREP][4 * NB];
  int   done[64];               // padded counter line
};

template <bool STASH>
__global__ __launch_bounds__(BS1) void pass1_k(const float4* __restrict__ p4,
                                               const float4* __restrict__ y4,
                                               const float4* __restrict__ w4,
                                               const float*  __restrict__ yraw,
                                               Accum* __restrict__ acc,
                                               float* __restrict__ su,
                                               float* __restrict__ sb, int N) {
  __shared__ int sh_l0;
  if (blockIdx.x == 0) {        // zero ghist + done (visible at kernel boundary)
    for (int i = threadIdx.x; i < GREP * 4 * NB; i += BS1) ((float*)acc->ghist)[i] = 0.f;
    if (threadIdx.x == 0) acc->done[0] = 0;
  }
  if (threadIdx.x == 0) {
    float best = yraw[0]; int bi = 0;
#pragma unroll
    for (int j = 1; j < C; ++j) { if (yraw[j] > best) { best = yraw[j]; bi = j; } }
    sh_l0 = bi;
    if (blockIdx.x == 0) acc->l0 = bi;
  }
  __syncthreads();
  const int l0   = sh_l0;
  const int q    = threadIdx.x & 1;          // channel half (0: ch0-3, 1: ch4-7)
  const int T    = blockIdx.x * BS1 + threadIdx.x;
  const int S    = NBLK1 * BS1;
  const int twoN = 2 * N;                    // f4s per array (even; pairs intact)

  float fsum = 0.f, csum = 0.f;
  float umin = __uint_as_float(0x7F800000u), umax = 0.f;

  for (int idx = T; idx < twoN; idx += S) {
    float4 pv = p4[idx];
    float4 yv = y4[idx];
    float4 wv = w4[idx];
    float P[4] = {pv.x, pv.y, pv.z, pv.w};
    float Y[4] = {yv.x, yv.y, yv.z, yv.w};
    float W[4] = {wv.x, wv.y, wv.z, wv.w};
    float up = 0.f, cep = 0.f, fop = 0.f;
    float cmax = P[0]; int pid = 0;
#pragma unroll
    for (int j = 0; j < 4; ++j) {
      if (j > 0 && P[j] > cmax) { cmax = P[j]; pid = j; }  // first-occurrence
      float le = __logf(fmaxf(P[j], 1e-10f));              // entropy log (EPS=1e-10)
      up -= P[j] * le;
      float lf = fmaxf(le, LOG_FEPS);                      // = log(max(p,1e-8))
      float t  = Y[j] * lf;
      cep -= t; fop -= t * W[j];
    }
    pid += 4 * q;
    fsum += fop; csum += cep;                // each lane adds its own half
    float unc = up + __shfl_xor(up, 1);
    float oc  = __shfl_xor(cmax, 1);
    int   op  = __shfl_xor(pid, 1);
    float lo_c = q ? oc : cmax;  int lo_p = q ? op : pid;
    float hi_c = q ? cmax : oc;  int hi_p = q ? pid : op;
    float conf = (hi_c > lo_c) ? hi_c : lo_c;   // ties -> low half (first occ.)
    int   pred = (hi_c > lo_c) ? hi_p : lo_p;
    umin = fminf(umin, unc); umax = fmaxf(umax, unc);
    if (STASH && q == 0) {                   // even lanes own the sample
      bool  corr = (pred == l0);
      float base = corr ? conf : (1.f - conf);
      int   i    = idx >> 1;
      su[i] = unc;
      sb[i] = corr ? base : -base;           // sign bit = !correct
    }
  }

  float v0 = fsum, v1 = csum, v2 = umin, v3 = umax;
#pragma unroll
  for (int o = 32; o > 0; o >>= 1) {
    v0 += __shfl_down(v0, o); v1 += __shfl_down(v1, o);
    v2 = fminf(v2, __shfl_down(v2, o)); v3 = fmaxf(v3, __shfl_down(v3, o));
  }
  __shared__ float r0[4], r1[4], r2[4], r3[4];
  int ln = threadIdx.x & 63, wd = threadIdx.x >> 6;
  if (ln == 0) { r0[wd] = v0; r1[wd] = v1; r2[wd] = v2; r3[wd] = v3; }
  __syncthreads();
  if (threadIdx.x == 0) {
    acc->f_part[blockIdx.x]  = r0[0] + r0[1] + r0[2] + r0[3];
    acc->c_part[blockIdx.x]  = r1[0] + r1[1] + r1[2] + r1[3];
    acc->mn_part[blockIdx.x] = fminf(fminf(r2[0], r2[1]), fminf(r2[2], r2[3]));
    acc->mx_part[blockIdx.x] = fmaxf(fmaxf(r3[0], r3[1]), fmaxf(r3[2], r3[3]));
  }
}

template <int BS>
__device__ __forceinline__ void reduce_minmax(const Accum* __restrict__ acc,
                                              float& out_umin, float& out_scale) {
  __shared__ float rmn[BS / 64], rmx[BS / 64];
  __shared__ float sh_umin, sh_umax;
  float mn = __uint_as_float(0x7F800000u), mx = 0.f;
  for (int i = threadIdx.x; i < NBLK1; i += BS) {
    mn = fminf(mn, acc->mn_part[i]);
    mx = fmaxf(mx, acc->mx_part[i]);
  }
#pragma unroll
  for (int o = 32; o > 0; o >>= 1) {
    mn = fminf(mn, __shfl_down(mn, o));
    mx = fmaxf(mx, __shfl_down(mx, o));
  }
  int lane = threadIdx.x & 63, wid = threadIdx.x >> 6;
  if (lane == 0) { rmn[wid] = mn; rmx[wid] = mx; }
  __syncthreads();
  if (threadIdx.x == 0) {
    float a = rmn[0], b = rmx[0];
#pragma unroll
    for (int wv = 1; wv < BS / 64; ++wv) { a = fminf(a, rmn[wv]); b = fmaxf(b, rmx[wv]); }
    sh_umin = a; sh_umax = b;
  }
  __syncthreads();
  out_umin = sh_umin; out_scale = sh_umax - sh_umin;
}

// Branchless first-satisfied-threshold (bit-identical comparisons to reference).
__device__ __forceinline__ int bin_of(float u, float umin, float scale) {
  int t0 = NB - 1;
#pragma unroll
  for (int t = NTH - 1; t >= 0; --t) {
    float thr = umin + ((float)t * 0.05f) * scale;
    if (u <= thr) t0 = t;                 // cndmask, no branch
  }
  return t0;
}

__device__ __forceinline__ void epilogue(const float* hist, double fsum, double csum,
                                         float* out, int N) {
  const float *hac = &hist[0], *hau = &hist[NB], *hic = &hist[2 * NB], *hiu = &hist[3 * NB];
  float tot_au = 0.f, tot_iu = 0.f;
  for (int s = 0; s < NB; ++s) { tot_au += hau[s]; tot_iu += hiu[s]; }
  float pac = 0.f, pau = 0.f, pic = 0.f, piu = 0.f, auc = 0.f, prev = 0.f;
  for (int t = 0; t < NTH; ++t) {
    pac += hac[t]; pau += hau[t]; pic += hic[t]; piu += hiu[t];
    float n_ac = pac, n_au = tot_au - pau, n_ic = pic, n_iu = tot_iu - piu;
    float avu = (n_ac + n_iu) / (n_ac + n_au + n_ic + n_iu + 1e-10f);
    if (t > 0) auc += 0.5f * (avu + prev) * 0.05f;
    prev = avu;
  }
  out[0] = -logf(auc + 1e-10f) + (float)(fsum / (double)N);  // BETA = 1
  out[1] = (float)(csum / (double)N);
}

__device__ __forceinline__ void quad(float* hb, float4 u4, float4 b4, int i4,
                                     float umin, float scale, int N) {
  float U[4] = {u4.x, u4.y, u4.z, u4.w};
  float B[4] = {b4.x, b4.y, b4.z, b4.w};
  int rem = N - (i4 << 2);
#pragma unroll
  for (int k = 0; k < 4; ++k) {
    if (k < rem) {
      float u = U[k], bs = B[k];
      float tu   = tanhf(u);
      float base = fabsf(bs);
      int   row  = (int)(__float_as_uint(bs) >> 31) * 2;  // sign = !correct
      int   t0   = bin_of(u, umin, scale);
      atomicAdd(&hb[row * NB + t0],       base * (1.f - tu));
      atomicAdd(&hb[(row + 1) * NB + t0], base * tu);
    }
  }
}

__global__ __launch_bounds__(BS2) void pass2_k(const float4* __restrict__ su4,
                                               const float4* __restrict__ sb4,
                                               Accum* __restrict__ acc,
                                               float* __restrict__ out, int N) {
  __shared__ float h[NREP * RSTR];
  for (int k = threadIdx.x; k < NREP * RSTR; k += BS2) h[k] = 0.f;
  float umin, scale;
  reduce_minmax<BS2>(acc, umin, scale);   // contains __syncthreads (covers h init)
  float* hb = &h[(threadIdx.x & (NREP - 1)) * RSTR];
  const int n4  = (N + 3) >> 2;
  const int STR = (int)gridDim.x * BS2;
  for (int ia = blockIdx.x * BS2 + threadIdx.x; ia < n4; ia += 2 * STR) {
    const int  ib = ia + STR;
    const bool vb = ib < n4;
    float4 ua = su4[ia], ba = sb4[ia];     // 4 loads issued before any compute
    float4 ub = make_float4(0.f, 0.f, 0.f, 0.f), bb = ub;
    if (vb) { ub = su4[ib]; bb = sb4[ib]; }
    quad(hb, ua, ba, ia, umin, scale, N);
    if (vb) quad(hb, ub, bb, ib, umin, scale, N);
  }
  __syncthreads();
  for (int idx = threadIdx.x; idx < 4 * NB; idx += BS2) {
    float s = 0.f;
#pragma unroll
    for (int r = 0; r < NREP; ++r) s += h[r * RSTR + idx];
    if (s != 0.f) atomicAdd(&acc->ghist[blockIdx.x & (GREP - 1)][idx], s);
  }
  __shared__ int amLast;
  __syncthreads();                         // drains flush atomics
  if (threadIdx.x == 0) {
    __threadfence();                       // release (1 per block, staggered)
    amLast = (atomicAdd(&acc->done[0], 1) == (int)gridDim.x - 1);
  }
  __syncthreads();
  if (!amLast) return;

  // ---------- last block: cheap tail ----------
  __threadfence();                         // acquire pairing
  __shared__ float gh[GREP * 4 * NB];      // 5.6 KB
  for (int j = threadIdx.x; j < GREP * 4 * NB; j += BS2)   // parallel coherent loads
    gh[j] = __hip_atomic_load(&((float*)acc->ghist)[j],
                              __ATOMIC_RELAXED, __HIP_MEMORY_SCOPE_AGENT);
  double f = 0.0, c = 0.0;
  for (int i = threadIdx.x; i < NBLK1; i += BS2) {
    f += (double)acc->f_part[i]; c += (double)acc->c_part[i];   // pass1 data: plain loads OK
  }
#pragma unroll
  for (int o = 32; o > 0; o >>= 1) { f += __shfl_down(f, o); c += __shfl_down(c, o); }
  __shared__ double df[BS2 / 64], dc[BS2 / 64];
  int lane = threadIdx.x & 63, wid = threadIdx.x >> 6;
  if (lane == 0) { df[wid] = f; dc[wid] = c; }
  __shared__ float hist[4 * NB];
  __syncthreads();
  if (threadIdx.x < 4 * NB) {
    float s = 0.f;
#pragma unroll
    for (int r = 0; r < GREP; ++r) s += gh[r * 4 * NB + threadIdx.x];
    hist[threadIdx.x] = s;
  }
  __syncthreads();
  if (threadIdx.x == 0) {
    double ft = 0.0, ct = 0.0;
#pragma unroll
    for (int wv = 0; wv < BS2 / 64; ++wv) { ft += df[wv]; ct += dc[wv]; }
    epilogue(hist, ft, ct, out, N);
  }
}

// ---------------- fallback path (no stash space): proven R8 structure ----------------
__global__ __launch_bounds__(BS2F) void pass2f_k(const float4* __restrict__ p4,
                                                 const Accum* __restrict__ acc,
                                                 float* __restrict__ partial2, int N) {
  __shared__ float h[NREP * RSTR];
  for (int k = threadIdx.x; k < NREP * RSTR; k += BS2F) h[k] = 0.f;
  float umin, scale;
  reduce_minmax<BS2F>(acc, umin, scale);
  const int l0 = acc->l0;
  float* hb = &h[(threadIdx.x & (NREP - 1)) * RSTR];
  int stride = gridDim.x * blockDim.x;
  for (int i = blockIdx.x * blockDim.x + threadIdx.x; i < N; i += stride) {
    float4 a = p4[2 * i], b = p4[2 * i + 1];
    float p[8] = {a.x, a.y, a.z, a.w, b.x, b.y, b.z, b.w};
    float conf = p[0]; int pred = 0;
    float unc = 0.f;
#pragma unroll
    for (int j = 0; j < 8; ++j) {
      if (p[j] > conf) { conf = p[j]; pred = j; }
      unc -= p[j] * __logf(fmaxf(p[j], 1e-10f));
    }
    bool corr = (pred == l0);
    float tu = tanhf(unc);
    float base = corr ? conf : (1.f - conf);
    int t0 = bin_of(unc, umin, scale);
    int row = corr ? 0 : 2;
    atomicAdd(&hb[row * NB + t0],       base * (1.f - tu));
    atomicAdd(&hb[(row + 1) * NB + t0], base * tu);
  }
  __syncthreads();
  for (int idx = threadIdx.x; idx < 4 * NB; idx += BS2F) {
    float s = 0.f;
#pragma unroll
    for (int r = 0; r < NREP; ++r) s += h[r * RSTR + idx];
    partial2[idx * NBLK2F + blockIdx.x] = s;
  }
}

__global__ __launch_bounds__(1024) void final_k(const float* __restrict__ partial2,
                                                const Accum* __restrict__ acc,
                                                float* __restrict__ out, int N) {
  __shared__ float hist[4 * NB];
  __shared__ double df[16], dc[16];
  int lane = threadIdx.x & 63, wid = threadIdx.x >> 6;
  double f = 0.0, c = 0.0;
  for (int i = threadIdx.x; i < NBLK1; i += 1024) {
    f += (double)acc->f_part[i]; c += (double)acc->c_part[i];
  }
#pragma unroll
  for (int o = 32; o > 0; o >>= 1) { f += __shfl_down(f, o); c += __shfl_down(c, o); }
  if (lane == 0) { df[wid] = f; dc[wid] = c; }
  for (int cidx = wid; cidx < 4 * NB; cidx += 16) {
    float s = 0.f;
    for (int k = lane; k < NBLK2F; k += 64) s += partial2[cidx * NBLK2F + k];
#pragma unroll
    for (int o = 32; o > 0; o >>= 1) s += __shfl_down(s, o);
    if (lane == 0) hist[cidx] = s;
  }
  __syncthreads();
  if (threadIdx.x == 0) {
    double ft = 0.0, ct = 0.0;
#pragma unroll
    for (int wv = 0; wv < 16; ++wv) { ft += df[wv]; ct += dc[wv]; }
    epilogue(hist, ft, ct, out, N);
  }
}

extern "C" void kernel_launch(void* const* d_in, const int* in_sizes, int n_in,
                              void* d_out, int out_size, void* d_ws, size_t ws_size,
                              hipStream_t stream) {
  const float* probs = (const float*)d_in[0];
  const float* y     = (const float*)d_in[1];
  const float* w     = (const float*)d_in[2];
  float* out = (float*)d_out;
  int N = in_sizes[0] / C;

  Accum* acc = (Accum*)d_ws;
  size_t off_p2 = (sizeof(Accum) + 255) & ~(size_t)255;
  size_t off_su = (off_p2 + (size_t)(4 * NB) * NBLK2F * sizeof(float) + 255) & ~(size_t)255;
  size_t one    = ((size_t)N * sizeof(float) + 255) & ~(size_t)255;
  size_t need   = off_su + 2 * one;
  float* partial2 = (float*)((char*)d_ws + off_p2);
  float* su = (float*)((char*)d_ws + off_su);
  float* sb = (float*)((char*)d_ws + off_su + one);

  if (ws_size >= need) {
    pass1_k<true><<<NBLK1, BS1, 0, stream>>>((const float4*)probs, (const float4*)y,
                                             (const float4*)w, y, acc, su, sb, N);
    pass2_k<<<NBLK2, BS2, 0, stream>>>((const float4*)su, (const float4*)sb, acc, out, N);
  } else {
    pass1_k<false><<<NBLK1, BS1, 0, stream>>>((const float4*)probs, (const float4*)y,
                                              (const float4*)w, y, acc, nullptr, nullptr, N);
    pass2f_k<<<NBLK2F, BS2F, 0, stream>>>((const float4*)probs, acc, partial2, N);
    final_k<<<1, 1024, 0, stream>>>(partial2, acc, out, N);
  }
}